// Round 21
// baseline (1179.085 us; speedup 1.0000x reference)
//
#include <hip/hip_runtime.h>
#include <stdint.h>

#define T_STEPS 1024
#define BATCH   512
#define INF     64
#define HID     128
#define OUTF    2

// d_out[0..1023] = z_sum [512][2], d_out[1024] = spikerate.
__global__ void zero_kernel(unsigned int* __restrict__ counter)
{
    *counter = 0u;
}

#define FOR16(M) M(0)M(1)M(2)M(3)M(4)M(5)M(6)M(7)M(8)M(9)M(10)M(11)M(12)M(13)M(14)M(15)

// =================== Kernel 1: batched input-path GEMM ===================
// pre[b][tc][h], bit-exact chains:
//   inp[t][b][h] = f32 seq-k (ascending, single acc) fmaf chain over x*W_in
//   pre[t][b][h] = f32 seq-j chain over inp*cWi
// k/j are the OUTER loops (weight loaded once per iter, used for 16 (t,b)
// outputs) -> per-accumulator op order is EXACTLY the ascending chain, and
// weight loads are loop-carried (not invariant) so nothing gets demoted.
__global__ __launch_bounds__(256)
void gemm_pre(const float* __restrict__ x,      // [T][B][64]
              const float* __restrict__ W_in,   // [128][64]
              const float* __restrict__ cWi,    // [128][128]
              float* __restrict__ pre,          // [B][tlen][128]
              int t0, int tlen)
{
    #pragma clang fp contract(off)
    __shared__ float xt[32 * INF];    // 8KB: x tile [32 b][64]
    __shared__ float it[32 * HID];    // 16KB: inp tile [32 b][128]

    const int tid = threadIdx.x;
    const int tc  = blockIdx.x >> 4;
    const int bt  = blockIdx.x & 15;
    const int t   = t0 + tc;
    const int b0  = bt * 32;

    {   // stage x tile (contiguous over (b,k))
        const float4* src = (const float4*)(x + ((size_t)t * BATCH + b0) * INF);
        float4* dst = (float4*)xt;
        dst[tid * 2 + 0] = src[tid * 2 + 0];
        dst[tid * 2 + 1] = src[tid * 2 + 1];
    }
    __syncthreads();

    const int h   = tid & (HID - 1);
    const int grp = tid >> 7;          // 0/1 -> bb range grp*16..grp*16+15

    // ---- pass1: inp (16 outputs per thread, weight row shared per k4)
    {
        #define DECLA(q) float a##q = 0.f;
        FOR16(DECLA)
        #undef DECLA
        const float4* wr  = (const float4*)(W_in + h * INF);
        const float4* xt4 = (const float4*)xt;
        for (int k4 = 0; k4 < INF / 4; ++k4) {
            float4 w = wr[k4];
            #define P1(q) { float4 xv = xt4[(grp * 16 + q) * (INF / 4) + k4]; \
                a##q = fmaf(xv.x, w.x, a##q); a##q = fmaf(xv.y, w.y, a##q); \
                a##q = fmaf(xv.z, w.z, a##q); a##q = fmaf(xv.w, w.w, a##q); }
            FOR16(P1)
            #undef P1
        }
        #define WR1(q) it[(grp * 16 + q) * HID + h] = a##q;
        FOR16(WR1)
        #undef WR1
    }
    __syncthreads();

    // ---- pass2: pre (16 outputs per thread, cWi row shared per j4)
    {
        #define DECLA(q) float a##q = 0.f;
        FOR16(DECLA)
        #undef DECLA
        const float4* cw  = (const float4*)(cWi + h * HID);
        const float4* it4 = (const float4*)it;
        for (int j4 = 0; j4 < HID / 4; ++j4) {
            float4 w = cw[j4];
            #define P2(q) { float4 iv = it4[(grp * 16 + q) * (HID / 4) + j4]; \
                a##q = fmaf(iv.x, w.x, a##q); a##q = fmaf(iv.y, w.y, a##q); \
                a##q = fmaf(iv.z, w.z, a##q); a##q = fmaf(iv.w, w.w, a##q); }
            FOR16(P2)
            #undef P2
        }
        #define WR2(q) pre[((size_t)(b0 + grp * 16 + q) * tlen + tc) * HID + h] = a##q;
        FOR16(WR2)
        #undef WR2
    }
}

// =================== Kernel 2: recurrent scan (no in-loop barriers) ===================
// 256 blocks x 128 threads; wave wv handles row b = blockIdx*2+wv, 2 neurons/lane.
// Masks live in-wave via ballot; Wrec_T in LDS; pre prefetched 2-deep.
// State (v,i,masks,cnt) carried across T-chunks in workspace.
// RACE FIX (round 20 post-mortem): epilogue must __syncthreads() BEFORE reusing
// Wrec_T as the count buffer — wave 0 finishing early was overwriting the
// j=0/j=1 weight rows while wave 1 was still scanning (absmax 29.0).
__global__ __launch_bounds__(128)
void snn_scan(const float* __restrict__ pre,    // [B][tlen][128]
              const float* __restrict__ Wrec,   // [128][128]
              const float* __restrict__ W_out, const float* __restrict__ b_out,
              const float* __restrict__ v_th, const float* __restrict__ v_leak1,
              const float* __restrict__ v_reset, const float* __restrict__ tau_mem,
              const float* __restrict__ tau_syn,
              int tlen, int first, int last,
              double* __restrict__ vst, double* __restrict__ ist,
              unsigned long long* __restrict__ mst, unsigned int* __restrict__ cst,
              float* __restrict__ out, unsigned int* __restrict__ counter)
{
    #pragma clang fp contract(off)
    extern __shared__ float Wrec_T[];           // [128][128]: Wrec_T[j][h]=Wrec[h][j]

    const int tid = threadIdx.x;
    for (int idx = tid; idx < HID * HID; idx += 128)
        Wrec_T[idx] = Wrec[(idx & (HID - 1)) * HID + (idx >> 7)];

    const int wv = tid >> 6;
    const int l  = tid & 63;
    const int b  = blockIdx.x * 2 + wv;
    const int h0 = 2 * l, h1 = 2 * l + 1;

    const double vth0  = (double)v_th[h0],    vth1  = (double)v_th[h1];
    const double vleak = (double)v_leak1[0];
    const double vrs0  = (double)v_reset[h0], vrs1  = (double)v_reset[h1];
    const double dtm0  = 0.001 * (double)tau_mem[h0];
    const double dtm1  = 0.001 * (double)tau_mem[h1];
    const double dts0  = 0.001 * (double)tau_syn[h0];
    const double dts1  = 0.001 * (double)tau_syn[h1];

    double v0, v1, c0, c1;
    int cnt0, cnt1;
    unsigned long long me, mo;
    if (first) {
        v0 = v1 = c0 = c1 = 0.0; cnt0 = cnt1 = 0; me = mo = 0ull;
    } else {
        v0 = vst[(size_t)b * HID + h0]; v1 = vst[(size_t)b * HID + h1];
        c0 = ist[(size_t)b * HID + h0]; c1 = ist[(size_t)b * HID + h1];
        cnt0 = (int)cst[(size_t)b * HID + h0]; cnt1 = (int)cst[(size_t)b * HID + h1];
        me = mst[b * 2 + 0]; mo = mst[b * 2 + 1];
    }
    __syncthreads();                            // Wrec_T ready

    const float2* prow = (const float2*)(pre + (size_t)b * tlen * HID) + l;
    float2 pA = prow[0];
    float2 pB = prow[(size_t)((tlen > 1) ? 1 : 0) * 64];

    #define STEP(PP) { \
        double s00 = 0.0, s01 = 0.0, s10 = 0.0, s11 = 0.0; \
        { unsigned long long A = me, Bm = mo; \
          while (A | Bm) { \
            float2 w0 = make_float2(0.f, 0.f), w1 = w0, w2 = w0, w3 = w0, \
                   w4 = w0, w5 = w0, w6 = w0, w7 = w0; \
            if (A)  { int j = __builtin_ctzll(A);  A  &= A - 1;  w0 = *(const float2*)(Wrec_T + (2 * j) * HID + h0); } \
            if (A)  { int j = __builtin_ctzll(A);  A  &= A - 1;  w1 = *(const float2*)(Wrec_T + (2 * j) * HID + h0); } \
            if (A)  { int j = __builtin_ctzll(A);  A  &= A - 1;  w2 = *(const float2*)(Wrec_T + (2 * j) * HID + h0); } \
            if (A)  { int j = __builtin_ctzll(A);  A  &= A - 1;  w3 = *(const float2*)(Wrec_T + (2 * j) * HID + h0); } \
            if (Bm) { int j = __builtin_ctzll(Bm); Bm &= Bm - 1; w4 = *(const float2*)(Wrec_T + (2 * j + 1) * HID + h0); } \
            if (Bm) { int j = __builtin_ctzll(Bm); Bm &= Bm - 1; w5 = *(const float2*)(Wrec_T + (2 * j + 1) * HID + h0); } \
            if (Bm) { int j = __builtin_ctzll(Bm); Bm &= Bm - 1; w6 = *(const float2*)(Wrec_T + (2 * j + 1) * HID + h0); } \
            if (Bm) { int j = __builtin_ctzll(Bm); Bm &= Bm - 1; w7 = *(const float2*)(Wrec_T + (2 * j + 1) * HID + h0); } \
            s00 += (double)w0.x; s10 += (double)w0.y; \
            s01 += (double)w1.x; s11 += (double)w1.y; \
            s00 += (double)w2.x; s10 += (double)w2.y; \
            s01 += (double)w3.x; s11 += (double)w3.y; \
            s00 += (double)w4.x; s10 += (double)w4.y; \
            s01 += (double)w5.x; s11 += (double)w5.y; \
            s00 += (double)w6.x; s10 += (double)w6.y; \
            s01 += (double)w7.x; s11 += (double)w7.y; \
          } } \
        double rec0 = (s00 + s01); \
        double rec1 = (s10 + s11); \
        double vd0 = v0 + dtm0 * ((vleak - v0) + c0); \
        double id0 = c0 - dts0 * c0; \
        bool   z0  = (vd0 - vth0) > 0.0; \
        v0 = z0 ? vrs0 : vd0; \
        c0 = (id0 + (double)PP.x) + rec0; \
        cnt0 += z0 ? 1 : 0; \
        double vd1 = v1 + dtm1 * ((vleak - v1) + c1); \
        double id1 = c1 - dts1 * c1; \
        bool   z1  = (vd1 - vth1) > 0.0; \
        v1 = z1 ? vrs1 : vd1; \
        c1 = (id1 + (double)PP.y) + rec1; \
        cnt1 += z1 ? 1 : 0; \
        me = __ballot(z0); \
        mo = __ballot(z1); }

    for (int t = 0; t < tlen; t += 2) {
        const int nA = (t + 2 < tlen) ? t + 2 : tlen - 1;
        const int nB = (t + 3 < tlen) ? t + 3 : tlen - 1;
        float2 newA = prow[(size_t)nA * 64];
        float2 newB = prow[(size_t)nB * 64];
        { float2 pp = pA; STEP(pp) }
        { float2 pp = pB; STEP(pp) }
        pA = newA; pB = newB;
    }
    #undef STEP

    if (last) {
        __syncthreads();   // RACE FIX: both waves done scanning before LDS reuse
        // z_sum rows = (sum_t z) @ W_out.T + 1024*b_out ; global spike count
        float* cl = Wrec_T;                      // reuse LDS
        cl[wv * HID + h0] = (float)cnt0;         // counts <= 1024: exact
        cl[wv * HID + h1] = (float)cnt1;
        __syncthreads();
        if (tid < 2 * OUTF) {
            int row = tid >> 1, oo = tid & 1;
            double s = 0.0;
            for (int hh = 0; hh < HID; ++hh)
                s += (double)cl[row * HID + hh] * (double)W_out[oo * HID + hh];
            out[(size_t)(blockIdx.x * 2 + row) * OUTF + oo] =
                (float)(s + 1024.0 * (double)b_out[oo]);
        }
        if (tid == 0) {
            unsigned int tot = 0;
            for (int k2 = 0; k2 < 2 * HID; ++k2) tot += (unsigned int)cl[k2];
            atomicAdd(counter, tot);
        }
    } else {
        vst[(size_t)b * HID + h0] = v0; vst[(size_t)b * HID + h1] = v1;
        ist[(size_t)b * HID + h0] = c0; ist[(size_t)b * HID + h1] = c1;
        cst[(size_t)b * HID + h0] = (unsigned int)cnt0;
        cst[(size_t)b * HID + h1] = (unsigned int)cnt1;
        if (l == 0) { mst[b * 2 + 0] = me; mst[b * 2 + 1] = mo; }
    }
}

__global__ void finalize_kernel(float* __restrict__ out)
{
    unsigned int c = ((const unsigned int*)out)[BATCH * OUTF];
    out[BATCH * OUTF] = (float)c * 0x1p-26f;   // / (1024*512*128), exact pow2
}

extern "C" void kernel_launch(void* const* d_in, const int* in_sizes, int n_in,
                              void* d_out, int out_size, void* d_ws, size_t ws_size,
                              hipStream_t stream) {
    (void)in_sizes; (void)n_in; (void)out_size;

    const float* x       = (const float*)d_in[0];
    const float* W_in    = (const float*)d_in[1];
    const float* cWi     = (const float*)d_in[2];
    const float* cWr     = (const float*)d_in[3];
    const float* W_out   = (const float*)d_in[4];
    const float* b_out   = (const float*)d_in[5];
    // d_in[6] = alpha (unused in forward)
    const float* v_th    = (const float*)d_in[7];
    const float* v_leak  = (const float*)d_in[8];
    const float* v_reset = (const float*)d_in[9];
    const float* tau_mem = (const float*)d_in[10];
    const float* tau_syn = (const float*)d_in[11];
    float* out = (float*)d_out;
    unsigned int* counter = (unsigned int*)out + BATCH * OUTF;

    // ---- workspace layout: [pre chunk][state]
    const size_t state_bytes = (size_t)BATCH * HID * 8 * 2      // vst, ist
                             + (size_t)BATCH * 2 * 8            // mst
                             + (size_t)BATCH * HID * 4;         // cst
    size_t avail = (ws_size > state_bytes + 1024) ? ws_size - state_bytes - 1024 : 0;
    int t_chunk = (int)((avail / ((size_t)BATCH * HID * 4)));
    if (t_chunk > T_STEPS) t_chunk = T_STEPS;
    t_chunk &= ~1;
    if (t_chunk < 2) t_chunk = 2;   // minimal fallback (needs ~512KB ws)

    float* pre = (float*)d_ws;
    size_t pre_cap = ((size_t)BATCH * t_chunk * HID * 4 + 255) & ~(size_t)255;
    double* vst = (double*)((char*)d_ws + pre_cap);
    double* ist = vst + (size_t)BATCH * HID;
    unsigned long long* mst = (unsigned long long*)(ist + (size_t)BATCH * HID);
    unsigned int* cst = (unsigned int*)(mst + (size_t)BATCH * 2);

    zero_kernel<<<1, 1, 0, stream>>>(counter);

    for (int t0 = 0; t0 < T_STEPS; t0 += t_chunk) {
        int len = (t0 + t_chunk <= T_STEPS) ? t_chunk : (T_STEPS - t0);
        gemm_pre<<<dim3(len * 16), dim3(256), 0, stream>>>(
            x, W_in, cWi, pre, t0, len);
        snn_scan<<<dim3(BATCH / 2), dim3(128), HID * HID * sizeof(float), stream>>>(
            pre, cWr, W_out, b_out, v_th, v_leak, v_reset, tau_mem, tau_syn,
            len, (t0 == 0) ? 1 : 0, (t0 + len >= T_STEPS) ? 1 : 0,
            vst, ist, mst, cst, out, counter);
    }

    finalize_kernel<<<1, 1, 0, stream>>>(out);
}